// Round 6
// baseline (5936.780 us; speedup 1.0000x reference)
//
#include <hip/hip_runtime.h>
#include <hip/hip_cooperative_groups.h>
#include <math.h>

namespace cg = cooperative_groups;

#define NFEAT 512
#define NHID  256
#define NCLS  64
#define KHOP  10
#define LDSTRIDE 56   // bf16 elems; 112B rows -> 16B aligned, 2-way bank alias (free)
#define NXCD 8
#define FCHUNK 8192
#define COOPBLK 2048  // 8 blocks/CU x 256 CU -- exactly co-resident (launch_bounds(256,8))

typedef __attribute__((ext_vector_type(8))) short short8;
typedef __attribute__((ext_vector_type(4))) float f32x4;

__device__ __forceinline__ unsigned short f2bf(float f) {
    unsigned u = __float_as_uint(f);
    u += 0x7FFFu + ((u >> 16) & 1u);       // RNE
    return (unsigned short)(u >> 16);
}
__device__ __forceinline__ float bf2f(unsigned short h) {
    return __uint_as_float((unsigned)h << 16);
}

// src [K][N] fp32 -> dst [N][K] bf16 (transpose-cast, tiny matrices)
__global__ __launch_bounds__(256) void castT_kernel(const float* __restrict__ src,
                                                    unsigned short* __restrict__ dst,
                                                    int K, int N)
{
    int i = blockIdx.x * 256 + threadIdx.x;
    if (i < K * N) {
        int k = i / N, n = i % N;
        dst[(long)n * K + k] = f2bf(src[i]);
    }
}

// ---- MFMA GEMM1 fused-cast: hmid = relu(x @ W1 + b1), fp32 A in, bf16 out ----
__global__ __launch_bounds__(256) void mfma_gemm1_f32(
    const float* __restrict__ A, const unsigned short* __restrict__ BT,
    const float* __restrict__ bias, unsigned short* __restrict__ C, int M)
{
    __shared__ unsigned short As[64 * LDSTRIDE];
    __shared__ unsigned short Bs[256 * LDSTRIDE];
    const int tid = threadIdx.x;
    const int wave = tid >> 6, lane = tid & 63;
    const int quad = lane >> 4, l16 = lane & 15;
    const int m0 = blockIdx.x * 64;

    f32x4 acc[4][4] = {};
    const int srow = tid >> 2;           // 0..63
    const int schunk = (tid & 3) * 8;    // 0,8,16,24 (elems)

    for (int k0 = 0; k0 < NFEAT; k0 += 32) {
        {
            int rg = m0 + srow;
            short8 v = {};
            if (rg < M) {
                const float* p = A + (long)rg * NFEAT + k0 + schunk;
                float4 f0 = *(const float4*)p;
                float4 f1 = *(const float4*)(p + 4);
                v[0] = (short)f2bf(f0.x); v[1] = (short)f2bf(f0.y);
                v[2] = (short)f2bf(f0.z); v[3] = (short)f2bf(f0.w);
                v[4] = (short)f2bf(f1.x); v[5] = (short)f2bf(f1.y);
                v[6] = (short)f2bf(f1.z); v[7] = (short)f2bf(f1.w);
            }
            *(short8*)(As + srow * LDSTRIDE + schunk) = v;
        }
        #pragma unroll
        for (int i = 0; i < 4; i++) {
            int r = srow + i * 64;
            short8 v = *(const short8*)(BT + (long)r * NFEAT + k0 + schunk);
            *(short8*)(Bs + r * LDSTRIDE + schunk) = v;
        }
        __syncthreads();
        short8 af[4], bfr[4];
        #pragma unroll
        for (int mi = 0; mi < 4; mi++)
            af[mi] = *(const short8*)(As + (mi*16 + l16) * LDSTRIDE + quad*8);
        #pragma unroll
        for (int nj = 0; nj < 4; nj++)
            bfr[nj] = *(const short8*)(Bs + (wave*64 + nj*16 + l16) * LDSTRIDE + quad*8);
        #pragma unroll
        for (int mi = 0; mi < 4; mi++)
            #pragma unroll
            for (int nj = 0; nj < 4; nj++)
                acc[mi][nj] = __builtin_amdgcn_mfma_f32_16x16x32_bf16(af[mi], bfr[nj], acc[mi][nj], 0, 0, 0);
        __syncthreads();
    }

    #pragma unroll
    for (int mi = 0; mi < 4; mi++)
        #pragma unroll
        for (int r = 0; r < 4; r++) {
            int row = m0 + mi*16 + quad*4 + r;
            if (row >= M) continue;
            #pragma unroll
            for (int nj = 0; nj < 4; nj++) {
                int col = wave*64 + nj*16 + l16;
                float v = acc[mi][nj][r] + bias[col];
                C[(long)row * NHID + col] = f2bf(fmaxf(v, 0.f));
            }
        }
}

// ------- MFMA GEMM2: v = hmid@W2 + b2; s0 = bf16(dis*v); hidden = temp0*v ----
__global__ __launch_bounds__(256) void mfma_gemm2(
    const unsigned short* __restrict__ A, const unsigned short* __restrict__ BT,
    const float* __restrict__ bias, unsigned short* __restrict__ S,
    float* __restrict__ hidden, const float* __restrict__ temp,
    const float* __restrict__ dis, int M)
{
    __shared__ unsigned short As[128 * LDSTRIDE];
    __shared__ unsigned short Bs[64 * LDSTRIDE];
    const int tid = threadIdx.x;
    const int wave = tid >> 6, lane = tid & 63;
    const int quad = lane >> 4, l16 = lane & 15;
    const int m0 = blockIdx.x * 128;
    const float t0 = temp[0];

    f32x4 acc[2][4] = {};
    const int srow = tid >> 2;
    const int schunk = (tid & 3) * 8;

    for (int k0 = 0; k0 < NHID; k0 += 32) {
        #pragma unroll
        for (int i = 0; i < 2; i++) {
            int r = srow + i * 64;
            int rg = m0 + r;
            short8 v = {};
            if (rg < M) v = *(const short8*)(A + (long)rg * NHID + k0 + schunk);
            *(short8*)(As + r * LDSTRIDE + schunk) = v;
        }
        {
            short8 v = *(const short8*)(BT + (long)srow * NHID + k0 + schunk);
            *(short8*)(Bs + srow * LDSTRIDE + schunk) = v;
        }
        __syncthreads();
        short8 af[2], bfr[4];
        #pragma unroll
        for (int mi = 0; mi < 2; mi++)
            af[mi] = *(const short8*)(As + (wave*32 + mi*16 + l16) * LDSTRIDE + quad*8);
        #pragma unroll
        for (int nj = 0; nj < 4; nj++)
            bfr[nj] = *(const short8*)(Bs + (nj*16 + l16) * LDSTRIDE + quad*8);
        #pragma unroll
        for (int mi = 0; mi < 2; mi++)
            #pragma unroll
            for (int nj = 0; nj < 4; nj++)
                acc[mi][nj] = __builtin_amdgcn_mfma_f32_16x16x32_bf16(af[mi], bfr[nj], acc[mi][nj], 0, 0, 0);
        __syncthreads();
    }

    #pragma unroll
    for (int mi = 0; mi < 2; mi++)
        #pragma unroll
        for (int r = 0; r < 4; r++) {
            int row = m0 + wave*32 + mi*16 + quad*4 + r;
            if (row >= M) continue;
            float dr = dis[row];
            #pragma unroll
            for (int nj = 0; nj < 4; nj++) {
                int col = nj*16 + l16;
                float v = acc[mi][nj][r] + bias[col];
                long idx = (long)row * NCLS + col;
                S[idx] = f2bf(dr * v);
                hidden[idx] = t0 * v;
            }
        }
}

// ---------------- graph preprocessing ----------------
__global__ void count_kernel(const int* __restrict__ ei, int E, int* __restrict__ cnt)
{
    int e = blockIdx.x * blockDim.x + threadIdx.x;
    if (e < E) atomicAdd(&cnt[ei[E + e]], 1);
}

__global__ void dis_kernel(const int* __restrict__ cnt, float* __restrict__ dis, int Nn)
{
    int v = blockIdx.x * blockDim.x + threadIdx.x;
    if (v < Nn) dis[v] = rsqrtf((float)(cnt[v] + 1));
}

// block sums of padded counts (pad each node's degree to multiple of 8)
__global__ __launch_bounds__(256) void bsum_kernel(const int* __restrict__ cnt, int n,
                                                   int* __restrict__ bsum)
{
    __shared__ int ws[4];
    int i = blockIdx.x * 256 + threadIdx.x;
    int v = (i < n) ? ((cnt[i] + 7) & ~7) : 0;
    #pragma unroll
    for (int off = 1; off < 64; off <<= 1) v += __shfl_xor(v, off);
    if ((threadIdx.x & 63) == 0) ws[threadIdx.x >> 6] = v;
    __syncthreads();
    if (threadIdx.x == 0) bsum[blockIdx.x] = ws[0] + ws[1] + ws[2] + ws[3];
}

__global__ __launch_bounds__(512) void bscan_kernel(int* __restrict__ bsum, int nb)
{
    __shared__ int buf[512];
    int i = threadIdx.x;
    int v = (i < nb) ? bsum[i] : 0;
    buf[i] = v;
    __syncthreads();
    for (int off = 1; off < 512; off <<= 1) {
        int t = (i >= off) ? buf[i - off] : 0;
        __syncthreads();
        buf[i] += t;
        __syncthreads();
    }
    if (i < nb) bsum[i] = buf[i] - v;   // exclusive
}

__global__ __launch_bounds__(256) void pscan_kernel(const int* __restrict__ cnt, int n,
                                                    const int* __restrict__ bsum,
                                                    int* __restrict__ ptr)
{
    __shared__ int buf[256];
    int i = blockIdx.x * 256 + threadIdx.x;
    int v = (i < n) ? ((cnt[i] + 7) & ~7) : 0;
    buf[threadIdx.x] = v;
    __syncthreads();
    for (int off = 1; off < 256; off <<= 1) {
        int t = (threadIdx.x >= off) ? buf[threadIdx.x - off] : 0;
        __syncthreads();
        buf[threadIdx.x] += t;
        __syncthreads();
    }
    if (i < n) ptr[i] = bsum[blockIdx.x] + buf[threadIdx.x] - v;
    if (i == n - 1) ptr[n] = bsum[blockIdx.x] + buf[threadIdx.x];   // total padded
}

// XCD-striped CSR fill (R1-verified version: 141us, WRITE 172MB)
__global__ __launch_bounds__(256) void fill2_kernel(const int* __restrict__ ei, int E, int Nn,
                                                    const int* __restrict__ ptr,
                                                    int* __restrict__ fill,
                                                    int* __restrict__ adj)
{
    const int s     = blockIdx.x & (NXCD - 1);
    const int chunk = blockIdx.x >> 3;
    const int lo = (int)(((long)s * Nn) / NXCD);
    const int hi = (int)(((long)(s + 1) * Nn) / NXCD);
    const int base = chunk * FCHUNK;
    int lim = base + FCHUNK; if (lim > E) lim = E;
    const int* colp = ei + E;
    for (int e0 = base + threadIdx.x * 4; e0 < lim; e0 += 1024) {
        int4 c4 = *(const int4*)(colp + e0);
        int c;
        c = c4.x; if (c >= lo && c < hi) { int r = ei[e0];     int p = atomicAdd(&fill[c], 1); adj[ptr[c] + p] = r; }
        c = c4.y; if (c >= lo && c < hi) { int r = ei[e0 + 1]; int p = atomicAdd(&fill[c], 1); adj[ptr[c] + p] = r; }
        c = c4.z; if (c >= lo && c < hi) { int r = ei[e0 + 2]; int p = atomicAdd(&fill[c], 1); adj[ptr[c] + p] = r; }
        c = c4.w; if (c >= lo && c < hi) { int r = ei[e0 + 3]; int p = atomicAdd(&fill[c], 1); adj[ptr[c] + p] = r; }
    }
}

// pad each node's CSR tail with the dummy node id Nn (whose s-row is zero)
__global__ void padfill_kernel(const int* __restrict__ cnt, const int* __restrict__ ptr,
                               int* __restrict__ adj, int Nn)
{
    int v = blockIdx.x * 256 + threadIdx.x;
    if (v >= Nn) return;
    int b = ptr[v] + cnt[v], e = ptr[v + 1];
    for (int i = b; i < e; i++) adj[i] = Nn;
}

__global__ void zdum_kernel(unsigned short* __restrict__ sA,
                            unsigned short* __restrict__ sB, int Nn)
{
    int i = threadIdx.x;
    if (i < 64) sA[(long)Nn * NCLS + i] = 0;
    else        sB[(long)Nn * NCLS + (i - 64)] = 0;
}

// -------- fused K-hop propagation + log-softmax (cooperative kernel) --------
// One wave per node per grid-stride step, lane = class (R1-proven gather body,
// bit-identical math). grid.sync() replaces the 10 kernel-launch barriers;
// log-softmax runs after the last sync. Saves ~10 launch+drain overheads.
__global__ __launch_bounds__(256, 8) void prop_coop(
    unsigned short* __restrict__ sA, unsigned short* __restrict__ sB,
    float* __restrict__ hidden,
    const int* __restrict__ ptr, const int* __restrict__ adj,
    const float* __restrict__ dis, const float* __restrict__ temp,
    float* __restrict__ out, int Nn)
{
    cg::grid_group grid = cg::this_grid();
    const int wave = threadIdx.x >> 6, lane = threadIdx.x & 63;
    const int stride = gridDim.x * 4;
    const int vstart = blockIdx.x * 4 + wave;

    for (int k = 0; k < KHOP; k++) {
        const unsigned short* sin = (k & 1) ? sB : sA;
        unsigned short*       so  = (k & 1) ? sA : sB;
        const float tk = temp[k + 1];
        for (int v = vstart; v < Nn; v += stride) {
            const int beg = ptr[v], end = ptr[v + 1];
            const float d = dis[v];
            float acc = bf2f(sin[v * NCLS + lane]);   // self loop term

            for (int e = beg; e < end; e += 8) {
                int4 u0 = *(const int4*)(adj + e);
                int4 u1 = *(const int4*)(adj + e + 4);
                float a0 = bf2f(sin[u0.x * NCLS + lane]);
                float a1 = bf2f(sin[u0.y * NCLS + lane]);
                float a2 = bf2f(sin[u0.z * NCLS + lane]);
                float a3 = bf2f(sin[u0.w * NCLS + lane]);
                float a4 = bf2f(sin[u1.x * NCLS + lane]);
                float a5 = bf2f(sin[u1.y * NCLS + lane]);
                float a6 = bf2f(sin[u1.z * NCLS + lane]);
                float a7 = bf2f(sin[u1.w * NCLS + lane]);
                acc += ((a0 + a1) + (a2 + a3)) + ((a4 + a5) + (a6 + a7));
            }

            int idx = v * NCLS + lane;
            float h = d * acc;
            hidden[idx] += tk * h;
            so[idx] = f2bf(d * h);
        }
        __threadfence();
        grid.sync();
    }

    // ---- log-softmax ----
    for (int v = vstart; v < Nn; v += stride) {
        float x = hidden[(long)v * NCLS + lane];
        float m = x;
        #pragma unroll
        for (int off = 32; off > 0; off >>= 1) m = fmaxf(m, __shfl_xor(m, off));
        float s = __expf(x - m);
        #pragma unroll
        for (int off = 32; off > 0; off >>= 1) s += __shfl_xor(s, off);
        out[(long)v * NCLS + lane] = x - m - logf(s);
    }
}

// ---------------- launcher ----------------
extern "C" void kernel_launch(void* const* d_in, const int* in_sizes, int n_in,
                              void* d_out, int out_size, void* d_ws, size_t ws_size,
                              hipStream_t stream)
{
    const float* x    = (const float*)d_in[0];
    const int*   ei   = (const int*)  d_in[1];
    const float* W1   = (const float*)d_in[2];
    const float* b1   = (const float*)d_in[3];
    const float* W2   = (const float*)d_in[4];
    const float* b2   = (const float*)d_in[5];
    const float* temp = (const float*)d_in[6];

    const int Nn = in_sizes[0] / NFEAT;   // 100000
    const int E  = in_sizes[1] / 2;       // 3200000

    char* ws = (char*)d_ws;
    size_t off = 0;
    auto alloc = [&](size_t bytes) { size_t o = off; off += (bytes + 255) & ~255ull; return o; };

    size_t Epad = (size_t)E + 8ull * Nn;
    int*            adj    = (int*)           (ws + alloc(Epad * 4));
    unsigned short* sA     = (unsigned short*)(ws + alloc((size_t)(Nn + 1) * NCLS * 2));
    unsigned short* sB     = (unsigned short*)(ws + alloc((size_t)(Nn + 1) * NCLS * 2));
    float*          hidden = (float*)         (ws + alloc((size_t)Nn * NCLS * 4));
    unsigned short* hmid   = (unsigned short*)(ws + alloc((size_t)Nn * NHID * 2));
    unsigned short* W1T    = (unsigned short*)(ws + alloc((size_t)NFEAT * NHID * 2));
    unsigned short* W2T    = (unsigned short*)(ws + alloc((size_t)NHID * NCLS * 2));
    int*   cnt   = (int*)  (ws + alloc((size_t)Nn * 4));
    int*   fillb = (int*)  (ws + alloc((size_t)Nn * 4));
    float* dis   = (float*)(ws + alloc((size_t)Nn * 4));
    int*   ptr   = (int*)  (ws + alloc((size_t)(Nn + 1) * 4));
    int*   bsum  = (int*)  (ws + alloc(((size_t)Nn / 256 + 2) * 4));

    // ---- weight transposes ----
    castT_kernel<<<(NFEAT * NHID + 255) / 256, 256, 0, stream>>>(W1, W1T, NFEAT, NHID);
    castT_kernel<<<(NHID * NCLS + 255) / 256, 256, 0, stream>>>(W2, W2T, NHID, NCLS);

    // ---- GEMM1 (fused fp32->bf16 cast; x read exactly once) ----
    mfma_gemm1_f32<<<(Nn + 63) / 64, 256, 0, stream>>>(x, W1T, b1, hmid, Nn);

    // ---- CSR build ----
    hipMemsetAsync(cnt,   0, (size_t)Nn * 4, stream);
    hipMemsetAsync(fillb, 0, (size_t)Nn * 4, stream);
    count_kernel<<<(E + 255) / 256, 256, 0, stream>>>(ei, E, cnt);
    dis_kernel<<<(Nn + 255) / 256, 256, 0, stream>>>(cnt, dis, Nn);
    int nb = (Nn + 255) / 256;
    bsum_kernel<<<nb, 256, 0, stream>>>(cnt, Nn, bsum);
    bscan_kernel<<<1, 512, 0, stream>>>(bsum, nb);
    pscan_kernel<<<nb, 256, 0, stream>>>(cnt, Nn, bsum, ptr);
    int nch = (E + FCHUNK - 1) / FCHUNK;
    fill2_kernel<<<nch * NXCD, 256, 0, stream>>>(ei, E, Nn, ptr, fillb, adj);
    padfill_kernel<<<(Nn + 255) / 256, 256, 0, stream>>>(cnt, ptr, adj, Nn);
    zdum_kernel<<<1, 128, 0, stream>>>(sA, sB, Nn);

    // ---- GEMM2 (writes s0 bf16 + hidden fp32; needs dis) ----
    mfma_gemm2<<<(Nn + 127) / 128, 256, 0, stream>>>(hmid, W2T, b2, sA, hidden, temp, dis, Nn);

    // ---- fused K-hop propagation + log-softmax (cooperative) ----
    {
        float* outp = (float*)d_out;
        int nn = Nn;
        void* args[] = { (void*)&sA, (void*)&sB, (void*)&hidden, (void*)&ptr,
                         (void*)&adj, (void*)&dis, (void*)&temp, (void*)&outp,
                         (void*)&nn };
        hipLaunchCooperativeKernel((const void*)prop_coop, dim3(COOPBLK), dim3(256),
                                   args, 0, stream);
    }
}

// Round 7
// 1353.465 us; speedup vs baseline: 4.3864x; 4.3864x over previous
//
#include <hip/hip_runtime.h>
#include <math.h>

#define NFEAT 512
#define NHID  256
#define NCLS  64
#define KHOP  10
#define LDSTRIDE 56   // bf16 elems; 112B rows -> 16B aligned, 2-way bank alias (free)
#define NXCD 8
#define FCHUNK 8192

typedef __attribute__((ext_vector_type(8))) short short8;
typedef __attribute__((ext_vector_type(4))) float f32x4;

__device__ __forceinline__ unsigned short f2bf(float f) {
    unsigned u = __float_as_uint(f);
    u += 0x7FFFu + ((u >> 16) & 1u);       // RNE
    return (unsigned short)(u >> 16);
}
__device__ __forceinline__ float bf2f(unsigned short h) {
    return __uint_as_float((unsigned)h << 16);
}

// ---- prep: castT(W1)+castT(W2)+degree-count fused (independent work) -------
__global__ __launch_bounds__(256) void prep_kernel(
    const float* __restrict__ W1, const float* __restrict__ W2,
    unsigned short* __restrict__ W1T, unsigned short* __restrict__ W2T,
    const int* __restrict__ ei, int E, int* __restrict__ cnt)
{
    int b = blockIdx.x;
    if (b < 512) {                      // W1 [512][256] -> W1T [256][512]
        int i = b * 256 + threadIdx.x;
        int k = i / NHID, n = i % NHID;
        W1T[(long)n * NFEAT + k] = f2bf(W1[i]);
    } else if (b < 576) {               // W2 [256][64] -> W2T [64][256]
        int i = (b - 512) * 256 + threadIdx.x;
        int k = i / NCLS, n = i % NCLS;
        W2T[(long)n * NHID + k] = f2bf(W2[i]);
    } else {
        int e = (b - 576) * 256 + threadIdx.x;
        if (e < E) atomicAdd(&cnt[ei[E + e]], 1);
    }
}

// ---- MFMA GEMM1 fused-cast: hmid = relu(x @ W1 + b1), fp32 A in, bf16 out ----
__global__ __launch_bounds__(256) void mfma_gemm1_f32(
    const float* __restrict__ A, const unsigned short* __restrict__ BT,
    const float* __restrict__ bias, unsigned short* __restrict__ C, int M)
{
    __shared__ unsigned short As[64 * LDSTRIDE];
    __shared__ unsigned short Bs[256 * LDSTRIDE];
    const int tid = threadIdx.x;
    const int wave = tid >> 6, lane = tid & 63;
    const int quad = lane >> 4, l16 = lane & 15;
    const int m0 = blockIdx.x * 64;

    f32x4 acc[4][4] = {};
    const int srow = tid >> 2;           // 0..63
    const int schunk = (tid & 3) * 8;    // 0,8,16,24 (elems)

    for (int k0 = 0; k0 < NFEAT; k0 += 32) {
        {
            int rg = m0 + srow;
            short8 v = {};
            if (rg < M) {
                const float* p = A + (long)rg * NFEAT + k0 + schunk;
                float4 f0 = *(const float4*)p;
                float4 f1 = *(const float4*)(p + 4);
                v[0] = (short)f2bf(f0.x); v[1] = (short)f2bf(f0.y);
                v[2] = (short)f2bf(f0.z); v[3] = (short)f2bf(f0.w);
                v[4] = (short)f2bf(f1.x); v[5] = (short)f2bf(f1.y);
                v[6] = (short)f2bf(f1.z); v[7] = (short)f2bf(f1.w);
            }
            *(short8*)(As + srow * LDSTRIDE + schunk) = v;
        }
        #pragma unroll
        for (int i = 0; i < 4; i++) {
            int r = srow + i * 64;
            short8 v = *(const short8*)(BT + (long)r * NFEAT + k0 + schunk);
            *(short8*)(Bs + r * LDSTRIDE + schunk) = v;
        }
        __syncthreads();
        short8 af[4], bfr[4];
        #pragma unroll
        for (int mi = 0; mi < 4; mi++)
            af[mi] = *(const short8*)(As + (mi*16 + l16) * LDSTRIDE + quad*8);
        #pragma unroll
        for (int nj = 0; nj < 4; nj++)
            bfr[nj] = *(const short8*)(Bs + (wave*64 + nj*16 + l16) * LDSTRIDE + quad*8);
        #pragma unroll
        for (int mi = 0; mi < 4; mi++)
            #pragma unroll
            for (int nj = 0; nj < 4; nj++)
                acc[mi][nj] = __builtin_amdgcn_mfma_f32_16x16x32_bf16(af[mi], bfr[nj], acc[mi][nj], 0, 0, 0);
        __syncthreads();
    }

    #pragma unroll
    for (int mi = 0; mi < 4; mi++)
        #pragma unroll
        for (int r = 0; r < 4; r++) {
            int row = m0 + mi*16 + quad*4 + r;
            if (row >= M) continue;
            #pragma unroll
            for (int nj = 0; nj < 4; nj++) {
                int col = wave*64 + nj*16 + l16;
                float v = acc[mi][nj][r] + bias[col];
                C[(long)row * NHID + col] = f2bf(fmaxf(v, 0.f));
            }
        }
}

// ------- MFMA GEMM2: v = hmid@W2 + b2; s0 = bf16(dis*v); hidden = temp0*v ----
__global__ __launch_bounds__(256) void mfma_gemm2(
    const unsigned short* __restrict__ A, const unsigned short* __restrict__ BT,
    const float* __restrict__ bias, unsigned short* __restrict__ S,
    float* __restrict__ hidden, const float* __restrict__ temp,
    const float* __restrict__ dis, int M)
{
    __shared__ unsigned short As[128 * LDSTRIDE];
    __shared__ unsigned short Bs[64 * LDSTRIDE];
    const int tid = threadIdx.x;
    const int wave = tid >> 6, lane = tid & 63;
    const int quad = lane >> 4, l16 = lane & 15;
    const int m0 = blockIdx.x * 128;
    const float t0 = temp[0];

    f32x4 acc[2][4] = {};
    const int srow = tid >> 2;
    const int schunk = (tid & 3) * 8;

    for (int k0 = 0; k0 < NHID; k0 += 32) {
        #pragma unroll
        for (int i = 0; i < 2; i++) {
            int r = srow + i * 64;
            int rg = m0 + r;
            short8 v = {};
            if (rg < M) v = *(const short8*)(A + (long)rg * NHID + k0 + schunk);
            *(short8*)(As + r * LDSTRIDE + schunk) = v;
        }
        {
            short8 v = *(const short8*)(BT + (long)srow * NHID + k0 + schunk);
            *(short8*)(Bs + srow * LDSTRIDE + schunk) = v;
        }
        __syncthreads();
        short8 af[2], bfr[4];
        #pragma unroll
        for (int mi = 0; mi < 2; mi++)
            af[mi] = *(const short8*)(As + (wave*32 + mi*16 + l16) * LDSTRIDE + quad*8);
        #pragma unroll
        for (int nj = 0; nj < 4; nj++)
            bfr[nj] = *(const short8*)(Bs + (nj*16 + l16) * LDSTRIDE + quad*8);
        #pragma unroll
        for (int mi = 0; mi < 2; mi++)
            #pragma unroll
            for (int nj = 0; nj < 4; nj++)
                acc[mi][nj] = __builtin_amdgcn_mfma_f32_16x16x32_bf16(af[mi], bfr[nj], acc[mi][nj], 0, 0, 0);
        __syncthreads();
    }

    #pragma unroll
    for (int mi = 0; mi < 2; mi++)
        #pragma unroll
        for (int r = 0; r < 4; r++) {
            int row = m0 + wave*32 + mi*16 + quad*4 + r;
            if (row >= M) continue;
            float dr = dis[row];
            #pragma unroll
            for (int nj = 0; nj < 4; nj++) {
                int col = nj*16 + l16;
                float v = acc[mi][nj][r] + bias[col];
                long idx = (long)row * NCLS + col;
                S[idx] = f2bf(dr * v);
                hidden[idx] = t0 * v;
            }
        }
}

// ---- dis + block-sums fused (both read only cnt) ---------------------------
__global__ __launch_bounds__(256) void disbsum_kernel(const int* __restrict__ cnt, int n,
                                                      float* __restrict__ dis,
                                                      int* __restrict__ bsum)
{
    __shared__ int ws[4];
    int i = blockIdx.x * 256 + threadIdx.x;
    int c = (i < n) ? cnt[i] : 0;
    if (i < n) dis[i] = rsqrtf((float)(c + 1));
    int v = (i < n) ? ((c + 7) & ~7) : 0;
    #pragma unroll
    for (int off = 1; off < 64; off <<= 1) v += __shfl_xor(v, off);
    if ((threadIdx.x & 63) == 0) ws[threadIdx.x >> 6] = v;
    __syncthreads();
    if (threadIdx.x == 0) bsum[blockIdx.x] = ws[0] + ws[1] + ws[2] + ws[3];
}

__global__ __launch_bounds__(512) void bscan_kernel(int* __restrict__ bsum, int nb)
{
    __shared__ int buf[512];
    int i = threadIdx.x;
    int v = (i < nb) ? bsum[i] : 0;
    buf[i] = v;
    __syncthreads();
    for (int off = 1; off < 512; off <<= 1) {
        int t = (i >= off) ? buf[i - off] : 0;
        __syncthreads();
        buf[i] += t;
        __syncthreads();
    }
    if (i < nb) bsum[i] = buf[i] - v;   // exclusive
}

__global__ __launch_bounds__(256) void pscan_kernel(const int* __restrict__ cnt, int n,
                                                    const int* __restrict__ bsum,
                                                    int* __restrict__ ptr)
{
    __shared__ int buf[256];
    int i = blockIdx.x * 256 + threadIdx.x;
    int v = (i < n) ? ((cnt[i] + 7) & ~7) : 0;
    buf[threadIdx.x] = v;
    __syncthreads();
    for (int off = 1; off < 256; off <<= 1) {
        int t = (threadIdx.x >= off) ? buf[threadIdx.x - off] : 0;
        __syncthreads();
        buf[threadIdx.x] += t;
        __syncthreads();
    }
    if (i < n) ptr[i] = bsum[blockIdx.x] + buf[threadIdx.x] - v;
    if (i == n - 1) ptr[n] = bsum[blockIdx.x] + buf[threadIdx.x];   // total padded
}

// XCD-striped CSR fill (R1-verified version: 141us)
__global__ __launch_bounds__(256) void fill2_kernel(const int* __restrict__ ei, int E, int Nn,
                                                    const int* __restrict__ ptr,
                                                    int* __restrict__ fill,
                                                    int* __restrict__ adj)
{
    const int s     = blockIdx.x & (NXCD - 1);
    const int chunk = blockIdx.x >> 3;
    const int lo = (int)(((long)s * Nn) / NXCD);
    const int hi = (int)(((long)(s + 1) * Nn) / NXCD);
    const int base = chunk * FCHUNK;
    int lim = base + FCHUNK; if (lim > E) lim = E;
    const int* colp = ei + E;
    for (int e0 = base + threadIdx.x * 4; e0 < lim; e0 += 1024) {
        int4 c4 = *(const int4*)(colp + e0);
        int c;
        c = c4.x; if (c >= lo && c < hi) { int r = ei[e0];     int p = atomicAdd(&fill[c], 1); adj[ptr[c] + p] = r; }
        c = c4.y; if (c >= lo && c < hi) { int r = ei[e0 + 1]; int p = atomicAdd(&fill[c], 1); adj[ptr[c] + p] = r; }
        c = c4.z; if (c >= lo && c < hi) { int r = ei[e0 + 2]; int p = atomicAdd(&fill[c], 1); adj[ptr[c] + p] = r; }
        c = c4.w; if (c >= lo && c < hi) { int r = ei[e0 + 3]; int p = atomicAdd(&fill[c], 1); adj[ptr[c] + p] = r; }
    }
}

// ---- padfill + zdum fused (last block zeroes the dummy rows) --------------
__global__ __launch_bounds__(256) void padzdum_kernel(const int* __restrict__ cnt,
                                                      const int* __restrict__ ptr,
                                                      int* __restrict__ adj, int Nn, int nb,
                                                      unsigned short* __restrict__ sA,
                                                      unsigned short* __restrict__ sB)
{
    if ((int)blockIdx.x == nb) {
        int i = threadIdx.x;
        if (i < 64)       sA[(long)Nn * NCLS + i] = 0;
        else if (i < 128) sB[(long)Nn * NCLS + (i - 64)] = 0;
        return;
    }
    int v = blockIdx.x * 256 + threadIdx.x;
    if (v >= Nn) return;
    int b = ptr[v] + cnt[v], e = ptr[v + 1];
    for (int i = b; i < e; i++) adj[i] = Nn;
}

// -------- K-hop propagation: one wave/node, lane=class (R1-verified body) ---
__global__ __launch_bounds__(256) void prop_kernel(
    const unsigned short* __restrict__ sin, unsigned short* __restrict__ sout,
    float* __restrict__ hidden,
    const int* __restrict__ ptr, const int* __restrict__ adj,
    const float* __restrict__ dis, const float* __restrict__ temp, int k, int Nn)
{
    const int wave = threadIdx.x >> 6, lane = threadIdx.x & 63;
    const int v = blockIdx.x * 4 + wave;
    if (v >= Nn) return;

    const int beg = ptr[v], end = ptr[v + 1];
    const float d = dis[v];
    float acc = bf2f(sin[v * NCLS + lane]);   // self loop term

    for (int e = beg; e < end; e += 8) {
        int4 u0 = *(const int4*)(adj + e);
        int4 u1 = *(const int4*)(adj + e + 4);
        float a0 = bf2f(sin[u0.x * NCLS + lane]);
        float a1 = bf2f(sin[u0.y * NCLS + lane]);
        float a2 = bf2f(sin[u0.z * NCLS + lane]);
        float a3 = bf2f(sin[u0.w * NCLS + lane]);
        float a4 = bf2f(sin[u1.x * NCLS + lane]);
        float a5 = bf2f(sin[u1.y * NCLS + lane]);
        float a6 = bf2f(sin[u1.z * NCLS + lane]);
        float a7 = bf2f(sin[u1.w * NCLS + lane]);
        acc += ((a0 + a1) + (a2 + a3)) + ((a4 + a5) + (a6 + a7));
    }

    int idx = v * NCLS + lane;
    float h = d * acc;
    hidden[idx] += temp[k + 1] * h;
    sout[idx] = f2bf(d * h);
}

// -------- last hop fused with log-softmax (sout of hop K-1 is dead) ---------
__global__ __launch_bounds__(256) void proplast_kernel(
    const unsigned short* __restrict__ sin,
    const float* __restrict__ hidden,
    const int* __restrict__ ptr, const int* __restrict__ adj,
    const float* __restrict__ dis, const float* __restrict__ temp,
    float* __restrict__ out, int Nn)
{
    const int wave = threadIdx.x >> 6, lane = threadIdx.x & 63;
    const int v = blockIdx.x * 4 + wave;
    if (v >= Nn) return;

    const int beg = ptr[v], end = ptr[v + 1];
    const float d = dis[v];
    float acc = bf2f(sin[v * NCLS + lane]);   // self loop term

    for (int e = beg; e < end; e += 8) {
        int4 u0 = *(const int4*)(adj + e);
        int4 u1 = *(const int4*)(adj + e + 4);
        float a0 = bf2f(sin[u0.x * NCLS + lane]);
        float a1 = bf2f(sin[u0.y * NCLS + lane]);
        float a2 = bf2f(sin[u0.z * NCLS + lane]);
        float a3 = bf2f(sin[u0.w * NCLS + lane]);
        float a4 = bf2f(sin[u1.x * NCLS + lane]);
        float a5 = bf2f(sin[u1.y * NCLS + lane]);
        float a6 = bf2f(sin[u1.z * NCLS + lane]);
        float a7 = bf2f(sin[u1.w * NCLS + lane]);
        acc += ((a0 + a1) + (a2 + a3)) + ((a4 + a5) + (a6 + a7));
    }

    int idx = v * NCLS + lane;
    float h = d * acc;
    float x = hidden[idx] + temp[KHOP] * h;   // final hidden value, in-register

    // ---- log-softmax over the wave's 64 classes ----
    float m = x;
    #pragma unroll
    for (int off = 32; off > 0; off >>= 1) m = fmaxf(m, __shfl_xor(m, off));
    float s = __expf(x - m);
    #pragma unroll
    for (int off = 32; off > 0; off >>= 1) s += __shfl_xor(s, off);
    out[idx] = x - m - logf(s);
}

// ---------------- launcher ----------------
extern "C" void kernel_launch(void* const* d_in, const int* in_sizes, int n_in,
                              void* d_out, int out_size, void* d_ws, size_t ws_size,
                              hipStream_t stream)
{
    const float* x    = (const float*)d_in[0];
    const int*   ei   = (const int*)  d_in[1];
    const float* W1   = (const float*)d_in[2];
    const float* b1   = (const float*)d_in[3];
    const float* W2   = (const float*)d_in[4];
    const float* b2   = (const float*)d_in[5];
    const float* temp = (const float*)d_in[6];

    const int Nn = in_sizes[0] / NFEAT;   // 100000
    const int E  = in_sizes[1] / 2;       // 3200000

    char* ws = (char*)d_ws;
    size_t off = 0;
    auto alloc = [&](size_t bytes) { size_t o = off; off += (bytes + 255) & ~255ull; return o; };

    size_t Epad = (size_t)E + 8ull * Nn;
    int*            adj    = (int*)           (ws + alloc(Epad * 4));
    unsigned short* sA     = (unsigned short*)(ws + alloc((size_t)(Nn + 1) * NCLS * 2));
    unsigned short* sB     = (unsigned short*)(ws + alloc((size_t)(Nn + 1) * NCLS * 2));
    float*          hidden = (float*)         (ws + alloc((size_t)Nn * NCLS * 4));
    unsigned short* hmid   = (unsigned short*)(ws + alloc((size_t)Nn * NHID * 2));
    unsigned short* W1T    = (unsigned short*)(ws + alloc((size_t)NFEAT * NHID * 2));
    unsigned short* W2T    = (unsigned short*)(ws + alloc((size_t)NHID * NCLS * 2));
    int*   cnt   = (int*)  (ws + alloc((size_t)Nn * 4));
    int*   fillb = (int*)  (ws + alloc((size_t)Nn * 4));
    float* dis   = (float*)(ws + alloc((size_t)Nn * 4));
    int*   ptr   = (int*)  (ws + alloc((size_t)(Nn + 1) * 4));
    int*   bsum  = (int*)  (ws + alloc(((size_t)Nn / 256 + 2) * 4));

    // ---- prep: weight transposes + degree count (fused) ----
    hipMemsetAsync(cnt,   0, (size_t)Nn * 4, stream);
    hipMemsetAsync(fillb, 0, (size_t)Nn * 4, stream);
    prep_kernel<<<576 + (E + 255) / 256, 256, 0, stream>>>(W1, W2, W1T, W2T, ei, E, cnt);

    // ---- GEMM1 (fused fp32->bf16 cast; x read exactly once) ----
    mfma_gemm1_f32<<<(Nn + 63) / 64, 256, 0, stream>>>(x, W1T, b1, hmid, Nn);

    // ---- CSR build ----
    int nb = (Nn + 255) / 256;
    disbsum_kernel<<<nb, 256, 0, stream>>>(cnt, Nn, dis, bsum);
    bscan_kernel<<<1, 512, 0, stream>>>(bsum, nb);
    pscan_kernel<<<nb, 256, 0, stream>>>(cnt, Nn, bsum, ptr);
    int nch = (E + FCHUNK - 1) / FCHUNK;
    fill2_kernel<<<nch * NXCD, 256, 0, stream>>>(ei, E, Nn, ptr, fillb, adj);
    padzdum_kernel<<<nb + 1, 256, 0, stream>>>(cnt, ptr, adj, Nn, nb, sA, sB);

    // ---- GEMM2 (writes s0 bf16 + hidden fp32; needs dis) ----
    mfma_gemm2<<<(Nn + 127) / 128, 256, 0, stream>>>(hmid, W2T, b2, sA, hidden, temp, dis, Nn);

    // ---- K-hop propagation (hops 0..K-2), last hop fused with log-softmax ----
    int pg = (Nn + 3) / 4;
    for (int k = 0; k < KHOP - 1; k++) {
        const unsigned short* sin = (k & 1) ? sB : sA;
        unsigned short*       so  = (k & 1) ? sA : sB;
        prop_kernel<<<pg, 256, 0, stream>>>(sin, so, hidden, ptr, adj, dis, temp, k, Nn);
    }
    proplast_kernel<<<pg, 256, 0, stream>>>(sB, hidden, ptr, adj, dis, temp,
                                            (float*)d_out, Nn);
}